// Round 1
// baseline (2712.542 us; speedup 1.0000x reference)
//
#include <hip/hip_runtime.h>
#include <math.h>

// Problem constants
#define B_    2
#define S_    2048
#define HID_  2048
#define NH_   16
#define NKV_  4
#define D_    128
#define M_    4096            // B*S
#define SCALING_ 0.08838834764831845f   // 128^-0.5
#define NEG_BIG_ (-1.0e9f)

// Output layout (all float32, concatenated): out | q_int8 | q_scale | k_int8 | k_scale
// sizes: 8388608 | 8388608 | 16 | 8388608 | 16
//
// ws layout (floats): ctx[8388608] | kf[2097152] | vf[2097152] | qP[64]i | qC[64]i | hist[163840]i
// total ~51 MB required.

// ---------------------------------------------------------------------------
// Fused QKV GEMM: hs(4096x2048) @ {Wq(2048x2048), Wk(2048x512), Wv(2048x512)}
// 128x128 tile, K-step 8, 256 threads, 8x8 per-thread register tile.
// Stores remapped to (B, H, S, D) layout.
// ---------------------------------------------------------------------------
__global__ __launch_bounds__(256) void sgemm_qkv(
    const float* __restrict__ A, const float* __restrict__ Wq,
    const float* __restrict__ Wk, const float* __restrict__ Wv,
    float* __restrict__ qbuf, float* __restrict__ kfb, float* __restrict__ vfb)
{
    __shared__ __align__(16) float As[8][132];   // [k][row], padded
    __shared__ __align__(16) float Bs[8][132];   // [k][col]
    const int tid = threadIdx.x;
    const int tx = tid & 15, ty = tid >> 4;
    const int bx = blockIdx.x, by = blockIdx.y;

    const float* W; float* Cc; int N, hh, nh;
    if (bx < 16)      { W = Wq; Cc = qbuf; N = 2048; hh = bx;      nh = 16; }
    else if (bx < 20) { W = Wk; Cc = kfb;  N = 512;  hh = bx - 16; nh = 4;  }
    else              { W = Wv; Cc = vfb;  N = 512;  hh = bx - 20; nh = 4;  }
    const int row0 = by * 128;
    const int col0 = hh * 128;

    float acc[8][8];
    #pragma unroll
    for (int i = 0; i < 8; i++)
        #pragma unroll
        for (int j = 0; j < 8; j++) acc[i][j] = 0.f;

    const int ar = tid >> 1, ac4 = (tid & 1) * 4;      // A: 128 rows x 8 k
    const int bk = tid >> 5, bn4 = (tid & 31) * 4;     // B: 8 k x 128 n
    const float* Aptr = A + (row0 + ar) * 2048 + ac4;
    const float* Bptr = W + bk * N + col0 + bn4;

    for (int k0 = 0; k0 < 2048; k0 += 8) {
        const float4 av = *(const float4*)(Aptr + k0);
        const float4 bv = *(const float4*)(Bptr + k0 * N);
        __syncthreads();
        As[ac4 + 0][ar] = av.x; As[ac4 + 1][ar] = av.y;
        As[ac4 + 2][ar] = av.z; As[ac4 + 3][ar] = av.w;
        *(float4*)&Bs[bk][bn4] = bv;
        __syncthreads();
        #pragma unroll
        for (int kk = 0; kk < 8; kk++) {
            const float4 a0 = *(const float4*)&As[kk][ty * 8];
            const float4 a1 = *(const float4*)&As[kk][ty * 8 + 4];
            const float4 b0 = *(const float4*)&Bs[kk][tx * 8];
            const float4 b1 = *(const float4*)&Bs[kk][tx * 8 + 4];
            const float a[8] = {a0.x,a0.y,a0.z,a0.w,a1.x,a1.y,a1.z,a1.w};
            const float b[8] = {b0.x,b0.y,b0.z,b0.w,b1.x,b1.y,b1.z,b1.w};
            #pragma unroll
            for (int i = 0; i < 8; i++)
                #pragma unroll
                for (int j = 0; j < 8; j++) acc[i][j] += a[i] * b[j];
        }
    }

    // store to (b, head, s, d) layout
    #pragma unroll
    for (int i = 0; i < 8; i++) {
        const int r = row0 + ty * 8 + i;
        const int bb = r >> 11, s = r & 2047;
        float* rowp = Cc + ((bb * nh + hh) * 2048 + s) * 128 + tx * 8;
        float4 v0 = {acc[i][0], acc[i][1], acc[i][2], acc[i][3]};
        float4 v1 = {acc[i][4], acc[i][5], acc[i][6], acc[i][7]};
        *(float4*)(rowp)     = v0;
        *(float4*)(rowp + 4) = v1;
    }
}

// ---------------------------------------------------------------------------
// Output GEMM: ctx(4096x2048) @ Wo(2048x2048) -> out, plain row-major store
// ---------------------------------------------------------------------------
__global__ __launch_bounds__(256) void sgemm_o(
    const float* __restrict__ A, const float* __restrict__ W, float* __restrict__ C)
{
    __shared__ __align__(16) float As[8][132];
    __shared__ __align__(16) float Bs[8][132];
    const int tid = threadIdx.x;
    const int tx = tid & 15, ty = tid >> 4;
    const int row0 = blockIdx.y * 128, col0 = blockIdx.x * 128;

    float acc[8][8];
    #pragma unroll
    for (int i = 0; i < 8; i++)
        #pragma unroll
        for (int j = 0; j < 8; j++) acc[i][j] = 0.f;

    const int ar = tid >> 1, ac4 = (tid & 1) * 4;
    const int bk = tid >> 5, bn4 = (tid & 31) * 4;
    const float* Aptr = A + (row0 + ar) * 2048 + ac4;
    const float* Bptr = W + bk * 2048 + col0 + bn4;

    for (int k0 = 0; k0 < 2048; k0 += 8) {
        const float4 av = *(const float4*)(Aptr + k0);
        const float4 bv = *(const float4*)(Bptr + k0 * 2048);
        __syncthreads();
        As[ac4 + 0][ar] = av.x; As[ac4 + 1][ar] = av.y;
        As[ac4 + 2][ar] = av.z; As[ac4 + 3][ar] = av.w;
        *(float4*)&Bs[bk][bn4] = bv;
        __syncthreads();
        #pragma unroll
        for (int kk = 0; kk < 8; kk++) {
            const float4 a0 = *(const float4*)&As[kk][ty * 8];
            const float4 a1 = *(const float4*)&As[kk][ty * 8 + 4];
            const float4 b0 = *(const float4*)&Bs[kk][tx * 8];
            const float4 b1 = *(const float4*)&Bs[kk][tx * 8 + 4];
            const float a[8] = {a0.x,a0.y,a0.z,a0.w,a1.x,a1.y,a1.z,a1.w};
            const float b[8] = {b0.x,b0.y,b0.z,b0.w,b1.x,b1.y,b1.z,b1.w};
            #pragma unroll
            for (int i = 0; i < 8; i++)
                #pragma unroll
                for (int j = 0; j < 8; j++) acc[i][j] += a[i] * b[j];
        }
    }
    #pragma unroll
    for (int i = 0; i < 8; i++) {
        const int r = row0 + ty * 8 + i;
        float* rowp = C + r * 2048 + col0 + tx * 8;
        float4 v0 = {acc[i][0], acc[i][1], acc[i][2], acc[i][3]};
        float4 v1 = {acc[i][4], acc[i][5], acc[i][6], acc[i][7]};
        *(float4*)(rowp)     = v0;
        *(float4*)(rowp + 4) = v1;
    }
}

// ---------------------------------------------------------------------------
// RoPE, in-place on (B, nheads, S, D) buffer. One thread per (b,h,s,d<64) pair.
// ---------------------------------------------------------------------------
__global__ __launch_bounds__(256) void rope_k(
    float* __restrict__ buf, const float* __restrict__ cosb,
    const float* __restrict__ sinb, int nheads)
{
    const int t = blockIdx.x * 256 + threadIdx.x;   // b*nh*S*64 total
    const int d = t & 63;
    const int s = (t >> 6) & 2047;
    const int bh = t >> 17;            // b*nheads + h
    const int base = (bh * 2048 + s) * 128;
    const int b = bh / nheads;
    const int cbase = (b * 2048 + s) * 128;
    const float x1 = buf[base + d], x2 = buf[base + d + 64];
    const float c1 = cosb[cbase + d],      s1 = sinb[cbase + d];
    const float c2 = cosb[cbase + d + 64], s2 = sinb[cbase + d + 64];
    buf[base + d]      = x1 * c1 - x2 * s1;
    buf[base + d + 64] = x2 * c2 + x1 * s2;
}

// ---------------------------------------------------------------------------
// Flash attention (fp32, causal). Block = (qtile of 64, head, batch), 256 thr.
// BK=32 key tiles, online softmax. ctx stored as (B, S, NH*D).
// ---------------------------------------------------------------------------
__global__ __launch_bounds__(256) void attn_k(
    const float* __restrict__ q, const float* __restrict__ kfb,
    const float* __restrict__ vfb, float* __restrict__ ctx)
{
    __shared__ __align__(16) float Qs[64][129];
    __shared__ __align__(16) float Ks[32][129];  // reused as V[32][128]
    __shared__ __align__(16) float Ps[64][33];

    const int tid = threadIdx.x;
    const int tx = tid & 7, ty = tid >> 3;        // ty 0..31 ; rows 2*ty+{0,1}
    const int qt = blockIdx.x, h = blockIdx.y, b = blockIdx.z;
    const int q0 = qt * 64;
    const float* qbase = q   + ((b * 16 + h) * 2048 + q0) * 128;
    const float* kbase = kfb + ((b * 4 + (h >> 2)) * 2048) * 128;
    const float* vbase = vfb + ((b * 4 + (h >> 2)) * 2048) * 128;

    // load Q tile (64 x 128)
    #pragma unroll
    for (int it = 0; it < 8; it++) {
        const int f = it * 256 + tid;
        const int r = f >> 5, d4 = (f & 31) * 4;
        const float4 v = *(const float4*)(qbase + r * 128 + d4);
        Qs[r][d4] = v.x; Qs[r][d4 + 1] = v.y; Qs[r][d4 + 2] = v.z; Qs[r][d4 + 3] = v.w;
    }

    float m_i[2] = {-INFINITY, -INFINITY};
    float l_i[2] = {0.f, 0.f};
    float O[2][16];
    #pragma unroll
    for (int i = 0; i < 2; i++)
        #pragma unroll
        for (int j = 0; j < 16; j++) O[i][j] = 0.f;

    const int ntiles = q0 / 32 + 2;
    for (int kt = 0; kt < ntiles; kt++) {
        const int kt0 = kt * 32;
        __syncthreads();   // protect Ks/Vs & Ps from previous iteration
        #pragma unroll
        for (int it = 0; it < 4; it++) {
            const int f = it * 256 + tid;
            const int r = f >> 5, d4 = (f & 31) * 4;
            const float4 v = *(const float4*)(kbase + (kt0 + r) * 128 + d4);
            Ks[r][d4] = v.x; Ks[r][d4 + 1] = v.y; Ks[r][d4 + 2] = v.z; Ks[r][d4 + 3] = v.w;
        }
        __syncthreads();

        // phase 1: scores (2 rows x 4 cols per thread)
        float sacc[2][4];
        #pragma unroll
        for (int i = 0; i < 2; i++)
            #pragma unroll
            for (int j = 0; j < 4; j++) sacc[i][j] = 0.f;
        #pragma unroll 4
        for (int d = 0; d < 128; d++) {
            const float qa = Qs[2 * ty][d];
            const float qb = Qs[2 * ty + 1][d];
            const float k0v = Ks[4 * tx][d];
            const float k1v = Ks[4 * tx + 1][d];
            const float k2v = Ks[4 * tx + 2][d];
            const float k3v = Ks[4 * tx + 3][d];
            sacc[0][0] += qa * k0v; sacc[0][1] += qa * k1v;
            sacc[0][2] += qa * k2v; sacc[0][3] += qa * k3v;
            sacc[1][0] += qb * k0v; sacc[1][1] += qb * k1v;
            sacc[1][2] += qb * k2v; sacc[1][3] += qb * k3v;
        }

        // online softmax update
        #pragma unroll
        for (int i = 0; i < 2; i++) {
            const int qg = q0 + 2 * ty + i;
            float sv[4];
            #pragma unroll
            for (int j = 0; j < 4; j++) {
                const int kg = kt0 + 4 * tx + j;
                sv[j] = (kg > qg) ? NEG_BIG_ : sacc[i][j] * SCALING_;
            }
            float rm = fmaxf(fmaxf(sv[0], sv[1]), fmaxf(sv[2], sv[3]));
            rm = fmaxf(rm, __shfl_xor(rm, 1));
            rm = fmaxf(rm, __shfl_xor(rm, 2));
            rm = fmaxf(rm, __shfl_xor(rm, 4));
            const float mn = fmaxf(m_i[i], rm);
            const float alpha = expf(m_i[i] - mn);   // expf(-inf)=0 on first tile
            float p[4], rs = 0.f;
            #pragma unroll
            for (int j = 0; j < 4; j++) { p[j] = expf(sv[j] - mn); rs += p[j]; }
            rs += __shfl_xor(rs, 1);
            rs += __shfl_xor(rs, 2);
            rs += __shfl_xor(rs, 4);
            l_i[i] = l_i[i] * alpha + rs;
            m_i[i] = mn;
            #pragma unroll
            for (int jj = 0; jj < 16; jj++) O[i][jj] *= alpha;
            #pragma unroll
            for (int j = 0; j < 4; j++) Ps[2 * ty + i][4 * tx + j] = p[j];
        }
        __syncthreads();   // Ps visible; phase-1 reads of Ks complete

        // load V tile over Ks storage
        float* Vs = &Ks[0][0];   // [32][128]
        #pragma unroll
        for (int it = 0; it < 4; it++) {
            const int f = it * 256 + tid;
            const int r = f >> 5, d4 = (f & 31) * 4;
            const float4 v = *(const float4*)(vbase + (kt0 + r) * 128 + d4);
            *(float4*)&Vs[r * 128 + d4] = v;
        }
        __syncthreads();

        // phase 2: O += P @ V   (2 rows x 16 cols per thread, cols tx*16..)
        #pragma unroll 2
        for (int c = 0; c < 32; c++) {
            const float p0 = Ps[2 * ty][c];
            const float p1 = Ps[2 * ty + 1][c];
            const float* vp = &Vs[c * 128 + tx * 16];
            #pragma unroll
            for (int u = 0; u < 4; u++) {
                const float4 vv = *(const float4*)(vp + u * 4);
                O[0][u * 4 + 0] += p0 * vv.x; O[0][u * 4 + 1] += p0 * vv.y;
                O[0][u * 4 + 2] += p0 * vv.z; O[0][u * 4 + 3] += p0 * vv.w;
                O[1][u * 4 + 0] += p1 * vv.x; O[1][u * 4 + 1] += p1 * vv.y;
                O[1][u * 4 + 2] += p1 * vv.z; O[1][u * 4 + 3] += p1 * vv.w;
            }
        }
    }

    // epilogue: normalize + store ctx (B, S, NH*D)
    #pragma unroll
    for (int i = 0; i < 2; i++) {
        const float inv = 1.f / l_i[i];
        const int s = q0 + 2 * ty + i;
        float* dst = ctx + (b * 2048 + s) * 2048 + h * 128 + tx * 16;
        #pragma unroll
        for (int u = 0; u < 4; u++) {
            float4 v = {O[i][u*4+0] * inv, O[i][u*4+1] * inv,
                        O[i][u*4+2] * inv, O[i][u*4+3] * inv};
            *(float4*)(dst + u * 4) = v;
        }
    }
}

// ---------------------------------------------------------------------------
// Quantile via exact radix-select on |x| bit patterns.
// 40 jobs = 20 heads (16 q + 4 kv) x 2 ranks (521665, 521666 of 524288).
// Levels: bits [31:20] (4096 bins), [19:8] (4096), [7:0] (256).
// ---------------------------------------------------------------------------
__global__ void quant_init(int* __restrict__ qP, int* __restrict__ qC)
{
    const int t = threadIdx.x;
    if (t < 40) { qP[t] = 0; qC[t] = 0; }
}

__global__ __launch_bounds__(256) void hist_zero(int* __restrict__ hist)
{
    hist[blockIdx.x * 256 + threadIdx.x] = 0;
}

__global__ __launch_bounds__(256) void hist_build(
    const float* __restrict__ qbuf, const float* __restrict__ kfb,
    const int* __restrict__ qP, int* __restrict__ hist, int level)
{
    __shared__ int lh[4096];
    const int tid = threadIdx.x;
    const int job = blockIdx.x >> 5, sub = blockIdx.x & 31;
    for (int i = tid; i < 4096; i += 256) lh[i] = 0;
    __syncthreads();
    const int head = job >> 1;
    const int pref = qP[job];
    for (int it = 0; it < 64; it++) {
        const int e = sub * 16384 + it * 256 + tid;   // 0..524287 per head
        const int bb = e >> 18, off = e & 262143;
        float v;
        if (head < 16) v = qbuf[(bb * 16 + head) * 262144 + off];
        else           v = kfb[(bb * 4 + (head - 16)) * 262144 + off];
        const unsigned u = __float_as_uint(fabsf(v));
        int bin = -1;
        if (level == 0)      bin = (int)(u >> 20);                                  // <=2047
        else if (level == 1) { if ((int)(u >> 20) == pref) bin = (int)((u >> 8) & 4095u); }
        else                 { if ((int)(u >> 8)  == pref) bin = (int)(u & 255u); }
        if (bin >= 0) atomicAdd(&lh[bin], 1);
    }
    __syncthreads();
    for (int i = tid; i < 4096; i += 256) {
        const int c = lh[i];
        if (c) atomicAdd(&hist[job * 4096 + i], c);
    }
}

__global__ __launch_bounds__(256) void hist_scan(
    int* __restrict__ qP, int* __restrict__ qC,
    const int* __restrict__ hist, int level)
{
    __shared__ int psum[256];
    __shared__ int sel[2];
    const int job = blockIdx.x, tid = threadIdx.x;
    const int target = (job & 1) ? 521666 : 521665;
    const int t = target - qC[job];
    int loc[16]; int s = 0;
    const int* hb = hist + job * 4096 + tid * 16;
    #pragma unroll
    for (int i = 0; i < 16; i++) { loc[i] = hb[i]; s += loc[i]; }
    psum[tid] = s;
    __syncthreads();
    if (tid == 0) {
        int cum = 0, pick = 255, pcum = 0; bool fnd = false;
        for (int i = 0; i < 256; i++) {
            const int c = psum[i];
            if (!fnd && cum + c > t) { pick = i; pcum = cum; fnd = true; }
            cum += c;
        }
        if (!fnd) pcum = cum - psum[255];
        sel[0] = pick; sel[1] = pcum;
    }
    __syncthreads();
    if (tid == sel[0]) {
        int c = sel[1];
        int bin = 15;
        #pragma unroll
        for (int i = 0; i < 16; i++) {
            if (c + loc[i] > t) { bin = i; break; }
            c += loc[i];
        }
        const int gbin = tid * 16 + bin;
        int p = qP[job];
        if (level == 0)      p = gbin;
        else if (level == 1) p = (p << 12) | gbin;
        else                 p = (p << 8) | gbin;
        qP[job] = p;
        qC[job] = qC[job] + c;
    }
}

__global__ void finalize_scales(const int* __restrict__ qP,
                                float* __restrict__ q_scale, float* __restrict__ k_scale)
{
    const int tid = threadIdx.x;
    const double pos = 0.995 * 524287.0;
    const float fr = (float)(pos - floor(pos));   // 0.565
    if (tid < 16) {
        const float v0 = __uint_as_float((unsigned)qP[2 * tid]);
        const float v1 = __uint_as_float((unsigned)qP[2 * tid + 1]);
        const float am = v0 + fr * (v1 - v0);
        q_scale[tid] = fmaxf(am, 1e-6f) / 7.0f;
    } else if (tid < 32) {
        const int h = tid - 16;
        const int job = (16 + (h >> 2)) * 2;
        const float v0 = __uint_as_float((unsigned)qP[job]);
        const float v1 = __uint_as_float((unsigned)qP[job + 1]);
        const float am = v0 + fr * (v1 - v0);
        k_scale[h] = fmaxf(am, 1e-6f) / 7.0f;
    }
}

// ---------------------------------------------------------------------------
// Quantization. q in-place (same index); k gathers from (B,NKV,S,D) -> (B,NH,S,D)
// ---------------------------------------------------------------------------
__global__ __launch_bounds__(256) void quant_q(
    float* __restrict__ qbuf, const float* __restrict__ q_scale)
{
    const int i = blockIdx.x * 256 + threadIdx.x;
    const int h = (i >> 18) & 15;
    const float sc = q_scale[h];
    float v = rintf(qbuf[i] / sc);
    v = fminf(fmaxf(v, -7.f), 7.f);
    qbuf[i] = v;
}

__global__ __launch_bounds__(256) void quant_k(
    const float* __restrict__ kfb, float* __restrict__ kout,
    const float* __restrict__ k_scale)
{
    const int i = blockIdx.x * 256 + threadIdx.x;
    const int h = (i >> 18) & 15;
    const int bb = i >> 22;
    const int rest = i & 262143;
    const float v = kfb[(bb * 4 + (h >> 2)) * 262144 + rest];
    const float sc = k_scale[h];
    float qv = rintf(v / sc);
    qv = fminf(fmaxf(qv, -7.f), 7.f);
    kout[i] = qv;
}

// ---------------------------------------------------------------------------
extern "C" void kernel_launch(void* const* d_in, const int* in_sizes, int n_in,
                              void* d_out, int out_size, void* d_ws, size_t ws_size,
                              hipStream_t stream)
{
    const float* hs   = (const float*)d_in[0];
    const float* cosb = (const float*)d_in[1];
    const float* sinb = (const float*)d_in[2];
    // d_in[3] = attention_mask: pure causal, implemented inline in attn_k
    const float* Wq = (const float*)d_in[4];
    const float* Wk = (const float*)d_in[5];
    const float* Wv = (const float*)d_in[6];
    const float* Wo = (const float*)d_in[7];

    float* out     = (float*)d_out;
    float* qbuf    = out + 8388608;     // q fp32 (rope'd), quantized in-place
    float* q_scale = out + 16777216;
    float* kqout   = out + 16777232;
    float* k_scale = out + 25165840;

    float* wsf = (float*)d_ws;          // needs ~51 MB
    float* ctx = wsf;                   // (B, S, NH*D)
    float* kfb = wsf + 8388608;         // (B, NKV, S, D)
    float* vfb = wsf + 10485760;        // (B, NKV, S, D)
    int*   qP  = (int*)(wsf + 12582912);
    int*   qC  = qP + 64;
    int*   hist = qP + 128;             // 40*4096 ints

    sgemm_qkv<<<dim3(24, 32), 256, 0, stream>>>(hs, Wq, Wk, Wv, qbuf, kfb, vfb);
    rope_k<<<16384, 256, 0, stream>>>(qbuf, cosb, sinb, 16);
    rope_k<<<4096, 256, 0, stream>>>(kfb, cosb, sinb, 4);
    attn_k<<<dim3(32, 16, 2), 256, 0, stream>>>(qbuf, kfb, vfb, ctx);
    sgemm_o<<<dim3(16, 32), 256, 0, stream>>>(ctx, Wo, out);

    quant_init<<<1, 64, 0, stream>>>(qP, qC);
    for (int lvl = 0; lvl < 3; lvl++) {
        hist_zero<<<640, 256, 0, stream>>>(hist);
        hist_build<<<1280, 256, 0, stream>>>(qbuf, kfb, qP, hist, lvl);
        hist_scan<<<40, 256, 0, stream>>>(qP, qC, hist, lvl);
    }
    finalize_scales<<<1, 64, 0, stream>>>(qP, q_scale, k_scale);

    quant_q<<<32768, 256, 0, stream>>>(qbuf, q_scale);
    quant_k<<<32768, 256, 0, stream>>>(kfb, kqout, k_scale);
}

// Round 2
// 1300.426 us; speedup vs baseline: 2.0859x; 2.0859x over previous
//
#include <hip/hip_runtime.h>
#include <math.h>

// Problem constants
#define SCALING_ 0.08838834764831845f   // 128^-0.5
#define SM_C     0.12751741f            // SCALING * log2(e)

typedef __bf16 bf16;
typedef bf16 bf16x8 __attribute__((ext_vector_type(8)));
typedef bf16 bf16x4 __attribute__((ext_vector_type(4)));
typedef float f32x4 __attribute__((ext_vector_type(4)));

// ---------------------------------------------------------------------------
// Fused QKV GEMM (fp32 — exactness feeds int4 quantization).
// hs(4096x2048) @ {Wq(2048x2048), Wk(2048x512), Wv(2048x512)}
// ---------------------------------------------------------------------------
__global__ __launch_bounds__(256) void sgemm_qkv(
    const float* __restrict__ A, const float* __restrict__ Wq,
    const float* __restrict__ Wk, const float* __restrict__ Wv,
    float* __restrict__ qbuf, float* __restrict__ kfb, float* __restrict__ vfb)
{
    __shared__ __align__(16) float As[8][132];
    __shared__ __align__(16) float Bs[8][132];
    const int tid = threadIdx.x;
    const int tx = tid & 15, ty = tid >> 4;
    const int bx = blockIdx.x, by = blockIdx.y;

    const float* W; float* Cc; int N, hh, nh;
    if (bx < 16)      { W = Wq; Cc = qbuf; N = 2048; hh = bx;      nh = 16; }
    else if (bx < 20) { W = Wk; Cc = kfb;  N = 512;  hh = bx - 16; nh = 4;  }
    else              { W = Wv; Cc = vfb;  N = 512;  hh = bx - 20; nh = 4;  }
    const int row0 = by * 128;
    const int col0 = hh * 128;

    float acc[8][8];
    #pragma unroll
    for (int i = 0; i < 8; i++)
        #pragma unroll
        for (int j = 0; j < 8; j++) acc[i][j] = 0.f;

    const int ar = tid >> 1, ac4 = (tid & 1) * 4;
    const int bk = tid >> 5, bn4 = (tid & 31) * 4;
    const float* Aptr = A + (row0 + ar) * 2048 + ac4;
    const float* Bptr = W + bk * N + col0 + bn4;

    for (int k0 = 0; k0 < 2048; k0 += 8) {
        const float4 av = *(const float4*)(Aptr + k0);
        const float4 bv = *(const float4*)(Bptr + k0 * N);
        __syncthreads();
        As[ac4 + 0][ar] = av.x; As[ac4 + 1][ar] = av.y;
        As[ac4 + 2][ar] = av.z; As[ac4 + 3][ar] = av.w;
        *(float4*)&Bs[bk][bn4] = bv;
        __syncthreads();
        #pragma unroll
        for (int kk = 0; kk < 8; kk++) {
            const float4 a0 = *(const float4*)&As[kk][ty * 8];
            const float4 a1 = *(const float4*)&As[kk][ty * 8 + 4];
            const float4 b0 = *(const float4*)&Bs[kk][tx * 8];
            const float4 b1 = *(const float4*)&Bs[kk][tx * 8 + 4];
            const float a[8] = {a0.x,a0.y,a0.z,a0.w,a1.x,a1.y,a1.z,a1.w};
            const float b[8] = {b0.x,b0.y,b0.z,b0.w,b1.x,b1.y,b1.z,b1.w};
            #pragma unroll
            for (int i = 0; i < 8; i++)
                #pragma unroll
                for (int j = 0; j < 8; j++) acc[i][j] += a[i] * b[j];
        }
    }
    #pragma unroll
    for (int i = 0; i < 8; i++) {
        const int r = row0 + ty * 8 + i;
        const int bb = r >> 11, s = r & 2047;
        float* rowp = Cc + ((bb * nh + hh) * 2048 + s) * 128 + tx * 8;
        float4 v0 = {acc[i][0], acc[i][1], acc[i][2], acc[i][3]};
        float4 v1 = {acc[i][4], acc[i][5], acc[i][6], acc[i][7]};
        *(float4*)(rowp)     = v0;
        *(float4*)(rowp + 4) = v1;
    }
}

// ---------------------------------------------------------------------------
// RoPE in-place (fp32 exact) + fused bf16 copy for the attention path.
// ---------------------------------------------------------------------------
__global__ __launch_bounds__(256) void rope_cvt_k(
    float* __restrict__ buf, bf16* __restrict__ outb,
    const float* __restrict__ cosb, const float* __restrict__ sinb, int nheads)
{
    const int t = blockIdx.x * 256 + threadIdx.x;
    const int d = t & 63;
    const int s = (t >> 6) & 2047;
    const int bh = t >> 17;
    const int base = (bh * 2048 + s) * 128;
    const int b = (nheads == 16) ? (bh >> 4) : (bh >> 2);
    const int cbase = (b * 2048 + s) * 128;
    const float x1 = buf[base + d], x2 = buf[base + d + 64];
    const float c1 = cosb[cbase + d],      s1 = sinb[cbase + d];
    const float c2 = cosb[cbase + d + 64], s2 = sinb[cbase + d + 64];
    const float y1 = x1 * c1 - x2 * s1;
    const float y2 = x2 * c2 + x1 * s2;
    buf[base + d]       = y1;
    buf[base + d + 64]  = y2;
    outb[base + d]      = (bf16)y1;
    outb[base + d + 64] = (bf16)y2;
}

// ---------------------------------------------------------------------------
// V: (b,kh,s,d) fp32 -> (b,kh,d,s) bf16   (32x32 LDS tile transpose)
// ---------------------------------------------------------------------------
__global__ __launch_bounds__(256) void transpose_v(
    const float* __restrict__ V, bf16* __restrict__ Vt)
{
    __shared__ float t[32][33];
    const int s0 = blockIdx.x * 32, d0 = blockIdx.y * 32;
    const long base = (long)blockIdx.z * 262144;
    const int r = threadIdx.x >> 3, c4 = (threadIdx.x & 7) * 4;
    const float4 v = *(const float4*)(V + base + (s0 + r) * 128 + d0 + c4);
    t[r][c4] = v.x; t[r][c4+1] = v.y; t[r][c4+2] = v.z; t[r][c4+3] = v.w;
    __syncthreads();
    bf16x4 o = { (bf16)t[c4][r], (bf16)t[c4+1][r], (bf16)t[c4+2][r], (bf16)t[c4+3][r] };
    *(bf16x4*)(Vt + base + (d0 + r) * 2048 + s0 + c4) = o;
}

// ---------------------------------------------------------------------------
// Wo: (k,n) fp32 -> (n,k) bf16
// ---------------------------------------------------------------------------
__global__ __launch_bounds__(256) void transpose_wo(
    const float* __restrict__ W, bf16* __restrict__ Wt)
{
    __shared__ float t[32][33];
    const int n0 = blockIdx.x * 32, k0 = blockIdx.y * 32;
    const int r = threadIdx.x >> 3, c4 = (threadIdx.x & 7) * 4;
    const float4 v = *(const float4*)(W + (k0 + r) * 2048 + n0 + c4);
    t[r][c4] = v.x; t[r][c4+1] = v.y; t[r][c4+2] = v.z; t[r][c4+3] = v.w;
    __syncthreads();
    bf16x4 o = { (bf16)t[c4][r], (bf16)t[c4+1][r], (bf16)t[c4+2][r], (bf16)t[c4+3][r] };
    *(bf16x4*)(Wt + (n0 + r) * 2048 + k0 + c4) = o;
}

// ---------------------------------------------------------------------------
// Flash attention, bf16 MFMA 16x16x32. BQ=BK=64, 4 waves, 256 threads.
// A-frag: A[m=lane&15][k=quad*8+j]; B-frag: B[k=quad*8+j][n=lane&15];
// C/D: row=quad*4+reg, col=lane&15 (m89/m91-verified).
// ctx written directly as bf16 (B, S, NH*D).
// ---------------------------------------------------------------------------
__global__ __launch_bounds__(256) void attn_mfma(
    const bf16* __restrict__ qb, const bf16* __restrict__ kb,
    const bf16* __restrict__ vt, bf16* __restrict__ ctx)
{
    __shared__ bf16 Qs[64][136];   // +8 pad: b128 reads 2-way (free)
    __shared__ bf16 Ks[64][136];
    __shared__ bf16 Vt[128][72];   // [d][key], from pre-transposed global
    __shared__ bf16 Ps[64][72];    // P round-trip C-layout -> A-layout

    const int tid = threadIdx.x;
    const int lane = tid & 63, wave = tid >> 6;
    const int l16 = lane & 15, quad = lane >> 4;
    const int qt = 31 - blockIdx.x;           // big blocks first
    const int h = blockIdx.y, b = blockIdx.z;
    const int q0 = qt * 64;
    const int wrow = wave * 16;

    const bf16* qbase = qb + ((long)((b * 16 + h) * 2048 + q0)) * 128;
    const bf16* kbase = kb + ((long)((b * 4 + (h >> 2)) * 2048)) * 128;
    const bf16* vbase = vt + ((long)((b * 4 + (h >> 2)) * 128)) * 2048;

    // stage Q once
    #pragma unroll
    for (int it = 0; it < 4; it++) {
        const int f = it * 256 + tid;
        const int r = f >> 4, c8 = (f & 15) * 8;
        *(bf16x8*)&Qs[r][c8] = *(const bf16x8*)(qbase + r * 128 + c8);
    }
    __syncthreads();
    bf16x8 aQ[4];
    #pragma unroll
    for (int ks = 0; ks < 4; ks++)
        aQ[ks] = *(const bf16x8*)&Qs[wrow + l16][ks * 32 + quad * 8];

    float m_i[4] = {-INFINITY, -INFINITY, -INFINITY, -INFINITY};
    float l_i[4] = {0.f, 0.f, 0.f, 0.f};
    f32x4 O[8];
    #pragma unroll
    for (int n = 0; n < 8; n++) O[n] = (f32x4){0.f, 0.f, 0.f, 0.f};

    for (int kt = 0; kt <= qt; kt++) {
        const int kt0 = kt * 64;
        __syncthreads();
        // stage K (64 x 128, row-major)
        #pragma unroll
        for (int it = 0; it < 4; it++) {
            const int f = it * 256 + tid;
            const int r = f >> 4, c8 = (f & 15) * 8;
            *(bf16x8*)&Ks[r][c8] = *(const bf16x8*)(kbase + (kt0 + r) * 128 + c8);
        }
        // stage V^T (128 d x 64 keys)
        #pragma unroll
        for (int it = 0; it < 8; it++) {
            const int f = it * 256 + tid;
            const int d = f >> 4, k4 = (f & 15) * 4;
            *(bf16x4*)&Vt[d][k4] = *(const bf16x4*)(vbase + d * 2048 + kt0 + k4);
        }
        __syncthreads();

        // S = Q K^T  (wave strip: 16 q-rows x 64 keys)
        f32x4 S[4];
        #pragma unroll
        for (int nt = 0; nt < 4; nt++) S[nt] = (f32x4){0.f, 0.f, 0.f, 0.f};
        #pragma unroll
        for (int nt = 0; nt < 4; nt++) {
            #pragma unroll
            for (int ks = 0; ks < 4; ks++) {
                const bf16x8 bK = *(const bf16x8*)&Ks[nt * 16 + l16][ks * 32 + quad * 8];
                S[nt] = __builtin_amdgcn_mfma_f32_16x16x32_bf16(aQ[ks], bK, S[nt], 0, 0, 0);
            }
        }

        const bool diag = (kt == qt);
        // online softmax, C-layout (row = quad*4+i, col = l16)
        #pragma unroll
        for (int i = 0; i < 4; i++) {
            const int qr = q0 + wrow + quad * 4 + i;
            float sv[4];
            #pragma unroll
            for (int nt = 0; nt < 4; nt++) {
                float x = S[nt][i];
                if (diag && (kt0 + nt * 16 + l16 > qr)) x = -1e30f;
                sv[nt] = x;
            }
            float rm = fmaxf(fmaxf(sv[0], sv[1]), fmaxf(sv[2], sv[3]));
            rm = fmaxf(rm, __shfl_xor(rm, 1));
            rm = fmaxf(rm, __shfl_xor(rm, 2));
            rm = fmaxf(rm, __shfl_xor(rm, 4));
            rm = fmaxf(rm, __shfl_xor(rm, 8));
            const float mn = fmaxf(m_i[i], rm);
            const float alpha = exp2f((m_i[i] - mn) * SM_C);
            m_i[i] = mn;
            float rs = 0.f;
            #pragma unroll
            for (int nt = 0; nt < 4; nt++) {
                const float p = exp2f((sv[nt] - mn) * SM_C);
                rs += p;
                Ps[wrow + quad * 4 + i][nt * 16 + l16] = (bf16)p;
            }
            rs += __shfl_xor(rs, 1);
            rs += __shfl_xor(rs, 2);
            rs += __shfl_xor(rs, 4);
            rs += __shfl_xor(rs, 8);
            l_i[i] = l_i[i] * alpha + rs;
            #pragma unroll
            for (int n = 0; n < 8; n++) O[n][i] *= alpha;
        }

        // O += P V   (Ps rows are wave-private; DS ops in-order within wave)
        bf16x8 aP[2];
        aP[0] = *(const bf16x8*)&Ps[wrow + l16][quad * 8];
        aP[1] = *(const bf16x8*)&Ps[wrow + l16][32 + quad * 8];
        #pragma unroll
        for (int nt = 0; nt < 8; nt++) {
            #pragma unroll
            for (int ks = 0; ks < 2; ks++) {
                const bf16x8 bV = *(const bf16x8*)&Vt[nt * 16 + l16][ks * 32 + quad * 8];
                O[nt] = __builtin_amdgcn_mfma_f32_16x16x32_bf16(aP[ks], bV, O[nt], 0, 0, 0);
            }
        }
    }

    // epilogue: normalize, store ctx bf16 (B, S, NH*D)
    #pragma unroll
    for (int i = 0; i < 4; i++) {
        const float inv = 1.f / l_i[i];
        const int s = q0 + wrow + quad * 4 + i;
        bf16* dst = ctx + ((long)(b * 2048 + s)) * 2048 + h * 128;
        #pragma unroll
        for (int nt = 0; nt < 8; nt++)
            dst[nt * 16 + l16] = (bf16)(O[nt][i] * inv);
    }
}

// ---------------------------------------------------------------------------
// O-projection: ctx_bf16(4096x2048) @ Wo -> out fp32, via WoT[n][k] bf16.
// 128x128 tile, BK=32, 4 waves in 2x2, 16 MFMA : 8 ds_read_b128 (m97 ratio).
// ---------------------------------------------------------------------------
__global__ __launch_bounds__(256) void gemm_o_mfma(
    const bf16* __restrict__ A, const bf16* __restrict__ Bt,
    float* __restrict__ C)
{
    __shared__ bf16 As[128][40];
    __shared__ bf16 Bs[128][40];
    const int tid = threadIdx.x;
    const int lane = tid & 63, wave = tid >> 6;
    const int l16 = lane & 15, quad = lane >> 4;
    const int m0 = blockIdx.y * 128, n0 = blockIdx.x * 128;
    const int wm = (wave >> 1) * 64, wn = (wave & 1) * 64;

    f32x4 acc[4][4];
    #pragma unroll
    for (int i = 0; i < 4; i++)
        #pragma unroll
        for (int j = 0; j < 4; j++) acc[i][j] = (f32x4){0.f, 0.f, 0.f, 0.f};

    for (int k0 = 0; k0 < 2048; k0 += 32) {
        __syncthreads();
        #pragma unroll
        for (int it = 0; it < 2; it++) {
            const int f = it * 256 + tid;
            const int r = f >> 2, c8 = (f & 3) * 8;
            *(bf16x8*)&As[r][c8] = *(const bf16x8*)(A + (long)(m0 + r) * 2048 + k0 + c8);
        }
        #pragma unroll
        for (int it = 0; it < 2; it++) {
            const int f = it * 256 + tid;
            const int r = f >> 2, c8 = (f & 3) * 8;
            *(bf16x8*)&Bs[r][c8] = *(const bf16x8*)(Bt + (long)(n0 + r) * 2048 + k0 + c8);
        }
        __syncthreads();
        bf16x8 af[4], bf_[4];
        #pragma unroll
        for (int mt = 0; mt < 4; mt++)
            af[mt] = *(const bf16x8*)&As[wm + mt * 16 + l16][quad * 8];
        #pragma unroll
        for (int nt = 0; nt < 4; nt++)
            bf_[nt] = *(const bf16x8*)&Bs[wn + nt * 16 + l16][quad * 8];
        #pragma unroll
        for (int mt = 0; mt < 4; mt++)
            #pragma unroll
            for (int nt = 0; nt < 4; nt++)
                acc[mt][nt] = __builtin_amdgcn_mfma_f32_16x16x32_bf16(af[mt], bf_[nt], acc[mt][nt], 0, 0, 0);
    }

    #pragma unroll
    for (int mt = 0; mt < 4; mt++) {
        #pragma unroll
        for (int r = 0; r < 4; r++) {
            const int row = m0 + wm + mt * 16 + quad * 4 + r;
            float* dst = C + (long)row * 2048 + n0 + wn;
            #pragma unroll
            for (int nt = 0; nt < 4; nt++)
                dst[nt * 16 + l16] = acc[mt][nt][r];
        }
    }
}

// ---------------------------------------------------------------------------
// Exact 0.995-quantile via radix-select on |x| bit patterns (unchanged).
// ---------------------------------------------------------------------------
__global__ void quant_init(int* __restrict__ qP, int* __restrict__ qC)
{
    const int t = threadIdx.x;
    if (t < 40) { qP[t] = 0; qC[t] = 0; }
}

__global__ __launch_bounds__(256) void hist_zero(int* __restrict__ hist)
{
    hist[blockIdx.x * 256 + threadIdx.x] = 0;
}

__global__ __launch_bounds__(256) void hist_build(
    const float* __restrict__ qbuf, const float* __restrict__ kfb,
    const int* __restrict__ qP, int* __restrict__ hist, int level)
{
    __shared__ int lh[4096];
    const int tid = threadIdx.x;
    const int job = blockIdx.x >> 5, sub = blockIdx.x & 31;
    for (int i = tid; i < 4096; i += 256) lh[i] = 0;
    __syncthreads();
    const int head = job >> 1;
    const int pref = qP[job];
    for (int it = 0; it < 64; it++) {
        const int e = sub * 16384 + it * 256 + tid;
        const int bb = e >> 18, off = e & 262143;
        float v;
        if (head < 16) v = qbuf[(bb * 16 + head) * 262144 + off];
        else           v = kfb[(bb * 4 + (head - 16)) * 262144 + off];
        const unsigned u = __float_as_uint(fabsf(v));
        int bin = -1;
        if (level == 0)      bin = (int)(u >> 20);
        else if (level == 1) { if ((int)(u >> 20) == pref) bin = (int)((u >> 8) & 4095u); }
        else                 { if ((int)(u >> 8)  == pref) bin = (int)(u & 255u); }
        if (bin >= 0) atomicAdd(&lh[bin], 1);
    }
    __syncthreads();
    for (int i = tid; i < 4096; i += 256) {
        const int c = lh[i];
        if (c) atomicAdd(&hist[job * 4096 + i], c);
    }
}

__global__ __launch_bounds__(256) void hist_scan(
    int* __restrict__ qP, int* __restrict__ qC,
    const int* __restrict__ hist, int level)
{
    __shared__ int psum[256];
    __shared__ int sel[2];
    const int job = blockIdx.x, tid = threadIdx.x;
    const int target = (job & 1) ? 521666 : 521665;
    const int t = target - qC[job];
    int loc[16]; int s = 0;
    const int* hb = hist + job * 4096 + tid * 16;
    #pragma unroll
    for (int i = 0; i < 16; i++) { loc[i] = hb[i]; s += loc[i]; }
    psum[tid] = s;
    __syncthreads();
    if (tid == 0) {
        int cum = 0, pick = 255, pcum = 0; bool fnd = false;
        for (int i = 0; i < 256; i++) {
            const int c = psum[i];
            if (!fnd && cum + c > t) { pick = i; pcum = cum; fnd = true; }
            cum += c;
        }
        if (!fnd) pcum = cum - psum[255];
        sel[0] = pick; sel[1] = pcum;
    }
    __syncthreads();
    if (tid == sel[0]) {
        int c = sel[1];
        int bin = 15;
        #pragma unroll
        for (int i = 0; i < 16; i++) {
            if (c + loc[i] > t) { bin = i; break; }
            c += loc[i];
        }
        const int gbin = tid * 16 + bin;
        int p = qP[job];
        if (level == 0)      p = gbin;
        else if (level == 1) p = (p << 12) | gbin;
        else                 p = (p << 8) | gbin;
        qP[job] = p;
        qC[job] = qC[job] + c;
    }
}

__global__ void finalize_scales(const int* __restrict__ qP,
                                float* __restrict__ q_scale, float* __restrict__ k_scale)
{
    const int tid = threadIdx.x;
    const double pos = 0.995 * 524287.0;
    const float fr = (float)(pos - floor(pos));
    if (tid < 16) {
        const float v0 = __uint_as_float((unsigned)qP[2 * tid]);
        const float v1 = __uint_as_float((unsigned)qP[2 * tid + 1]);
        const float am = v0 + fr * (v1 - v0);
        q_scale[tid] = fmaxf(am, 1e-6f) / 7.0f;
    } else if (tid < 32) {
        const int h = tid - 16;
        const int job = (16 + (h >> 2)) * 2;
        const float v0 = __uint_as_float((unsigned)qP[job]);
        const float v1 = __uint_as_float((unsigned)qP[job + 1]);
        const float am = v0 + fr * (v1 - v0);
        k_scale[h] = fmaxf(am, 1e-6f) / 7.0f;
    }
}

__global__ __launch_bounds__(256) void quant_q(
    float* __restrict__ qbuf, const float* __restrict__ q_scale)
{
    const int i = blockIdx.x * 256 + threadIdx.x;
    const int h = (i >> 18) & 15;
    const float sc = q_scale[h];
    float v = rintf(qbuf[i] / sc);
    v = fminf(fmaxf(v, -7.f), 7.f);
    qbuf[i] = v;
}

__global__ __launch_bounds__(256) void quant_k(
    const float* __restrict__ kfb, float* __restrict__ kout,
    const float* __restrict__ k_scale)
{
    const int i = blockIdx.x * 256 + threadIdx.x;
    const int h = (i >> 18) & 15;
    const int bb = i >> 22;
    const int rest = i & 262143;
    const float v = kfb[(bb * 4 + (h >> 2)) * 262144 + rest];
    const float sc = k_scale[h];
    float qv = rintf(v / sc);
    qv = fminf(fmaxf(qv, -7.f), 7.f);
    kout[i] = qv;
}

// ---------------------------------------------------------------------------
extern "C" void kernel_launch(void* const* d_in, const int* in_sizes, int n_in,
                              void* d_out, int out_size, void* d_ws, size_t ws_size,
                              hipStream_t stream)
{
    const float* hs   = (const float*)d_in[0];
    const float* cosb = (const float*)d_in[1];
    const float* sinb = (const float*)d_in[2];
    const float* Wq = (const float*)d_in[4];
    const float* Wk = (const float*)d_in[5];
    const float* Wv = (const float*)d_in[6];
    const float* Wo = (const float*)d_in[7];

    float* out     = (float*)d_out;
    float* qbuf    = out + 8388608;     // q fp32 (rope'd), quantized in-place
    float* q_scale = out + 16777216;
    float* kqout   = out + 16777232;    // k_int8 region: doubles as bf16 scratch
    float* k_scale = out + 25165840;

    // bf16 scratch inside the (written-last) k_int8 region: 25.2 MB of 33.5 MB
    bf16* qb16 = (bf16*)kqout;
    bf16* kb16 = qb16 + 8388608;
    bf16* vtb  = kb16 + 2097152;

    float* wsf = (float*)d_ws;          // ~43 MB used
    bf16*  ctx16 = (bf16*)wsf;                 // 8.4M bf16 = 4.2M floats
    float* kfb   = wsf + 4194304;              // (B,NKV,S,D) fp32
    float* vfb   = wsf + 6291456;
    bf16*  woT   = (bf16*)(wsf + 8388608);     // WoT[n][k] bf16
    int*   qP    = (int*)(wsf + 10485760);
    int*   qC    = qP + 64;
    int*   hist  = qP + 128;

    sgemm_qkv<<<dim3(24, 32), 256, 0, stream>>>(hs, Wq, Wk, Wv, qbuf, kfb, vfb);
    rope_cvt_k<<<16384, 256, 0, stream>>>(qbuf, qb16, cosb, sinb, 16);
    rope_cvt_k<<<4096, 256, 0, stream>>>(kfb, kb16, cosb, sinb, 4);
    transpose_v<<<dim3(64, 4, 8), 256, 0, stream>>>(vfb, vtb);
    transpose_wo<<<dim3(64, 64), 256, 0, stream>>>(Wo, woT);

    attn_mfma<<<dim3(32, 16, 2), 256, 0, stream>>>(qb16, kb16, vtb, ctx16);
    gemm_o_mfma<<<dim3(16, 32), 256, 0, stream>>>(ctx16, woT, out);

    quant_init<<<1, 64, 0, stream>>>(qP, qC);
    for (int lvl = 0; lvl < 3; lvl++) {
        hist_zero<<<640, 256, 0, stream>>>(hist);
        hist_build<<<1280, 256, 0, stream>>>(qbuf, kfb, qP, hist, lvl);
        hist_scan<<<40, 256, 0, stream>>>(qP, qC, hist, lvl);
    }
    finalize_scales<<<1, 64, 0, stream>>>(qP, q_scale, k_scale);

    quant_q<<<32768, 256, 0, stream>>>(qbuf, q_scale);
    quant_k<<<32768, 256, 0, stream>>>(kfb, kqout, k_scale);
}

// Round 6
// 1257.798 us; speedup vs baseline: 2.1566x; 1.0339x over previous
//
#include <hip/hip_runtime.h>
#include <math.h>

// Problem constants
#define SCALING_ 0.08838834764831845f   // 128^-0.5
#define SM_C     0.12751741f            // SCALING * log2(e)

typedef __bf16 bf16;
typedef bf16 bf16x8 __attribute__((ext_vector_type(8)));
typedef bf16 bf16x4 __attribute__((ext_vector_type(4)));
typedef float f32x4 __attribute__((ext_vector_type(4)));

// ---------------------------------------------------------------------------
// Fused QKV GEMM — fp32 VALU, arithmetic bit-identical to the R1/R2 kernel:
// each output accumulates acc += A[r][k]*B[k][c] for k = 0..2047 strictly
// ascending (v_fmac). Optimizations vs R1 (none change per-output order):
//  - B column groups {tx*4, 64+tx*4}: LDS reads hit all 8 superbanks (2-way,
//    free) instead of 4 (4-way tax) — kills the 5e7 bank conflicts.
//  - register prefetch of next K-tile global loads (latency hidden).
//  - BK=16: half the barriers.
// ---------------------------------------------------------------------------
__global__ __launch_bounds__(256) void sgemm_qkv(
    const float* __restrict__ A, const float* __restrict__ Wq,
    const float* __restrict__ Wk, const float* __restrict__ Wv,
    float* __restrict__ qbuf, float* __restrict__ kfb, float* __restrict__ vfb)
{
    __shared__ __align__(16) float As[16][132];   // [k][row]
    __shared__ __align__(16) float Bs[16][132];   // [k][col]
    const int tid = threadIdx.x;
    const int tx = tid & 15, ty = tid >> 4;
    const int bx = blockIdx.x, by = blockIdx.y;

    const float* W; float* Cc; int N, hh, nh;
    if (bx < 16)      { W = Wq; Cc = qbuf; N = 2048; hh = bx;      nh = 16; }
    else if (bx < 20) { W = Wk; Cc = kfb;  N = 512;  hh = bx - 16; nh = 4;  }
    else              { W = Wv; Cc = vfb;  N = 512;  hh = bx - 20; nh = 4;  }
    const int row0 = by * 128;
    const int col0 = hh * 128;

    float acc[8][8];
    #pragma unroll
    for (int i = 0; i < 8; i++)
        #pragma unroll
        for (int j = 0; j < 8; j++) acc[i][j] = 0.f;

    const int ar = tid >> 1, ac8 = (tid & 1) * 8;   // A: 128 rows x 16 k
    const int bk = tid >> 5, bn4 = (tid & 31) * 4;  // B: rows bk, bk+8; 128 cols
    const float* Aptr = A + (row0 + ar) * 2048 + ac8;
    const float* Bptr = W + bk * N + col0 + bn4;

    float4 a0 = *(const float4*)(Aptr);
    float4 a1 = *(const float4*)(Aptr + 4);
    float4 b0 = *(const float4*)(Bptr);
    float4 b1 = *(const float4*)(Bptr + 8 * N);

    for (int k0 = 0; k0 < 2048; k0 += 16) {
        __syncthreads();
        As[ac8 + 0][ar] = a0.x; As[ac8 + 1][ar] = a0.y;
        As[ac8 + 2][ar] = a0.z; As[ac8 + 3][ar] = a0.w;
        As[ac8 + 4][ar] = a1.x; As[ac8 + 5][ar] = a1.y;
        As[ac8 + 6][ar] = a1.z; As[ac8 + 7][ar] = a1.w;
        *(float4*)&Bs[bk][bn4]     = b0;
        *(float4*)&Bs[bk + 8][bn4] = b1;
        __syncthreads();
        if (k0 + 16 < 2048) {
            a0 = *(const float4*)(Aptr + k0 + 16);
            a1 = *(const float4*)(Aptr + k0 + 20);
            b0 = *(const float4*)(Bptr + (long)(k0 + 16) * N);
            b1 = *(const float4*)(Bptr + (long)(k0 + 24) * N);
        }
        #pragma unroll
        for (int kk = 0; kk < 16; kk++) {
            const float4 av0 = *(const float4*)&As[kk][ty * 8];
            const float4 av1 = *(const float4*)&As[kk][ty * 8 + 4];
            const float4 bv0 = *(const float4*)&Bs[kk][tx * 4];
            const float4 bv1 = *(const float4*)&Bs[kk][64 + tx * 4];
            const float a[8] = {av0.x,av0.y,av0.z,av0.w,av1.x,av1.y,av1.z,av1.w};
            const float b[8] = {bv0.x,bv0.y,bv0.z,bv0.w,bv1.x,bv1.y,bv1.z,bv1.w};
            #pragma unroll
            for (int i = 0; i < 8; i++)
                #pragma unroll
                for (int j = 0; j < 8; j++) acc[i][j] += a[i] * b[j];
        }
    }

    // store to (b, head, s, d): thread owns rows ty*8+i, cols tx*4..+3 and 64+tx*4..+3
    #pragma unroll
    for (int i = 0; i < 8; i++) {
        const int r = row0 + ty * 8 + i;
        const int bb = r >> 11, s = r & 2047;
        float* rowp = Cc + ((long)((bb * nh + hh) * 2048 + s)) * 128;
        float4 v0 = {acc[i][0], acc[i][1], acc[i][2], acc[i][3]};
        float4 v1 = {acc[i][4], acc[i][5], acc[i][6], acc[i][7]};
        *(float4*)(rowp + tx * 4)      = v0;
        *(float4*)(rowp + 64 + tx * 4) = v1;
    }
}

// ---------------------------------------------------------------------------
// RoPE in-place (fp32 exact) + fused bf16 copy for the attention path.
// ---------------------------------------------------------------------------
__global__ __launch_bounds__(256) void rope_cvt_k(
    float* __restrict__ buf, bf16* __restrict__ outb,
    const float* __restrict__ cosb, const float* __restrict__ sinb, int nheads)
{
    const int t = blockIdx.x * 256 + threadIdx.x;
    const int d = t & 63;
    const int s = (t >> 6) & 2047;
    const int bh = t >> 17;
    const int base = (bh * 2048 + s) * 128;
    const int b = (nheads == 16) ? (bh >> 4) : (bh >> 2);
    const int cbase = (b * 2048 + s) * 128;
    const float x1 = buf[base + d], x2 = buf[base + d + 64];
    const float c1 = cosb[cbase + d],      s1 = sinb[cbase + d];
    const float c2 = cosb[cbase + d + 64], s2 = sinb[cbase + d + 64];
    const float y1 = x1 * c1 - x2 * s1;
    const float y2 = x2 * c2 + x1 * s2;
    buf[base + d]       = y1;
    buf[base + d + 64]  = y2;
    outb[base + d]      = (bf16)y1;
    outb[base + d + 64] = (bf16)y2;
}

// ---------------------------------------------------------------------------
// V: (b,kh,s,d) fp32 -> (b,kh,d,s) bf16   (32x32 LDS tile transpose)
// ---------------------------------------------------------------------------
__global__ __launch_bounds__(256) void transpose_v(
    const float* __restrict__ V, bf16* __restrict__ Vt)
{
    __shared__ float t[32][33];
    const int s0 = blockIdx.x * 32, d0 = blockIdx.y * 32;
    const long base = (long)blockIdx.z * 262144;
    const int r = threadIdx.x >> 3, c4 = (threadIdx.x & 7) * 4;
    const float4 v = *(const float4*)(V + base + (s0 + r) * 128 + d0 + c4);
    t[r][c4] = v.x; t[r][c4+1] = v.y; t[r][c4+2] = v.z; t[r][c4+3] = v.w;
    __syncthreads();
    bf16x4 o = { (bf16)t[c4][r], (bf16)t[c4+1][r], (bf16)t[c4+2][r], (bf16)t[c4+3][r] };
    *(bf16x4*)(Vt + base + (d0 + r) * 2048 + s0 + c4) = o;
}

// ---------------------------------------------------------------------------
// Wo: (k,n) fp32 -> (n,k) bf16
// ---------------------------------------------------------------------------
__global__ __launch_bounds__(256) void transpose_wo(
    const float* __restrict__ W, bf16* __restrict__ Wt)
{
    __shared__ float t[32][33];
    const int n0 = blockIdx.x * 32, k0 = blockIdx.y * 32;
    const int r = threadIdx.x >> 3, c4 = (threadIdx.x & 7) * 4;
    const float4 v = *(const float4*)(W + (k0 + r) * 2048 + n0 + c4);
    t[r][c4] = v.x; t[r][c4+1] = v.y; t[r][c4+2] = v.z; t[r][c4+3] = v.w;
    __syncthreads();
    bf16x4 o = { (bf16)t[c4][r], (bf16)t[c4+1][r], (bf16)t[c4+2][r], (bf16)t[c4+3][r] };
    *(bf16x4*)(Wt + (n0 + r) * 2048 + k0 + c4) = o;
}

// ---------------------------------------------------------------------------
// Flash attention, bf16 MFMA 16x16x32. BQ=BK=64, 4 waves, 256 threads.
// ---------------------------------------------------------------------------
__global__ __launch_bounds__(256) void attn_mfma(
    const bf16* __restrict__ qb, const bf16* __restrict__ kb,
    const bf16* __restrict__ vt, bf16* __restrict__ ctx)
{
    __shared__ bf16 Qs[64][136];
    __shared__ bf16 Ks[64][136];
    __shared__ bf16 Vt[128][72];
    __shared__ bf16 Ps[64][72];

    const int tid = threadIdx.x;
    const int lane = tid & 63, wave = tid >> 6;
    const int l16 = lane & 15, quad = lane >> 4;
    const int qt = 31 - blockIdx.x;           // big blocks first
    const int h = blockIdx.y, b = blockIdx.z;
    const int q0 = qt * 64;
    const int wrow = wave * 16;

    const bf16* qbase = qb + ((long)((b * 16 + h) * 2048 + q0)) * 128;
    const bf16* kbase = kb + ((long)((b * 4 + (h >> 2)) * 2048)) * 128;
    const bf16* vbase = vt + ((long)((b * 4 + (h >> 2)) * 128)) * 2048;

    #pragma unroll
    for (int it = 0; it < 4; it++) {
        const int f = it * 256 + tid;
        const int r = f >> 4, c8 = (f & 15) * 8;
        *(bf16x8*)&Qs[r][c8] = *(const bf16x8*)(qbase + r * 128 + c8);
    }
    __syncthreads();
    bf16x8 aQ[4];
    #pragma unroll
    for (int ks = 0; ks < 4; ks++)
        aQ[ks] = *(const bf16x8*)&Qs[wrow + l16][ks * 32 + quad * 8];

    float m_i[4] = {-INFINITY, -INFINITY, -INFINITY, -INFINITY};
    float l_i[4] = {0.f, 0.f, 0.f, 0.f};
    f32x4 O[8];
    #pragma unroll
    for (int n = 0; n < 8; n++) O[n] = (f32x4){0.f, 0.f, 0.f, 0.f};

    for (int kt = 0; kt <= qt; kt++) {
        const int kt0 = kt * 64;
        __syncthreads();
        #pragma unroll
        for (int it = 0; it < 4; it++) {
            const int f = it * 256 + tid;
            const int r = f >> 4, c8 = (f & 15) * 8;
            *(bf16x8*)&Ks[r][c8] = *(const bf16x8*)(kbase + (kt0 + r) * 128 + c8);
        }
        #pragma unroll
        for (int it = 0; it < 8; it++) {
            const int f = it * 256 + tid;
            const int d = f >> 4, k4 = (f & 15) * 4;
            *(bf16x4*)&Vt[d][k4] = *(const bf16x4*)(vbase + d * 2048 + kt0 + k4);
        }
        __syncthreads();

        f32x4 S[4];
        #pragma unroll
        for (int nt = 0; nt < 4; nt++) S[nt] = (f32x4){0.f, 0.f, 0.f, 0.f};
        #pragma unroll
        for (int nt = 0; nt < 4; nt++) {
            #pragma unroll
            for (int ks = 0; ks < 4; ks++) {
                const bf16x8 bK = *(const bf16x8*)&Ks[nt * 16 + l16][ks * 32 + quad * 8];
                S[nt] = __builtin_amdgcn_mfma_f32_16x16x32_bf16(aQ[ks], bK, S[nt], 0, 0, 0);
            }
        }

        const bool diag = (kt == qt);
        #pragma unroll
        for (int i = 0; i < 4; i++) {
            const int qr = q0 + wrow + quad * 4 + i;
            float sv[4];
            #pragma unroll
            for (int nt = 0; nt < 4; nt++) {
                float x = S[nt][i];
                if (diag && (kt0 + nt * 16 + l16 > qr)) x = -1e30f;
                sv[nt] = x;
            }
            float rm = fmaxf(fmaxf(sv[0], sv[1]), fmaxf(sv[2], sv[3]));
            rm = fmaxf(rm, __shfl_xor(rm, 1));
            rm = fmaxf(rm, __shfl_xor(rm, 2));
            rm = fmaxf(rm, __shfl_xor(rm, 4));
            rm = fmaxf(rm, __shfl_xor(rm, 8));
            const float mn = fmaxf(m_i[i], rm);
            const float alpha = exp2f((m_i[i] - mn) * SM_C);
            m_i[i] = mn;
            float rs = 0.f;
            #pragma unroll
            for (int nt = 0; nt < 4; nt++) {
                const float p = exp2f((sv[nt] - mn) * SM_C);
                rs += p;
                Ps[wrow + quad * 4 + i][nt * 16 + l16] = (bf16)p;
            }
            rs += __shfl_xor(rs, 1);
            rs += __shfl_xor(rs, 2);
            rs += __shfl_xor(rs, 4);
            rs += __shfl_xor(rs, 8);
            l_i[i] = l_i[i] * alpha + rs;
            #pragma unroll
            for (int n = 0; n < 8; n++) O[n][i] *= alpha;
        }

        bf16x8 aP[2];
        aP[0] = *(const bf16x8*)&Ps[wrow + l16][quad * 8];
        aP[1] = *(const bf16x8*)&Ps[wrow + l16][32 + quad * 8];
        #pragma unroll
        for (int nt = 0; nt < 8; nt++) {
            #pragma unroll
            for (int ks = 0; ks < 2; ks++) {
                const bf16x8 bV = *(const bf16x8*)&Vt[nt * 16 + l16][ks * 32 + quad * 8];
                O[nt] = __builtin_amdgcn_mfma_f32_16x16x32_bf16(aP[ks], bV, O[nt], 0, 0, 0);
            }
        }
    }

    #pragma unroll
    for (int i = 0; i < 4; i++) {
        const float inv = 1.f / l_i[i];
        const int s = q0 + wrow + quad * 4 + i;
        bf16* dst = ctx + ((long)(b * 2048 + s)) * 2048 + h * 128;
        #pragma unroll
        for (int nt = 0; nt < 8; nt++)
            dst[nt * 16 + l16] = (bf16)(O[nt][i] * inv);
    }
}

// ---------------------------------------------------------------------------
// O-projection: ctx_bf16(4096x2048) @ Wo -> out fp32, via WoT[n][k] bf16.
// ---------------------------------------------------------------------------
__global__ __launch_bounds__(256) void gemm_o_mfma(
    const bf16* __restrict__ A, const bf16* __restrict__ Bt,
    float* __restrict__ C)
{
    __shared__ bf16 As[128][40];
    __shared__ bf16 Bs[128][40];
    const int tid = threadIdx.x;
    const int lane = tid & 63, wave = tid >> 6;
    const int l16 = lane & 15, quad = lane >> 4;
    const int m0 = blockIdx.y * 128, n0 = blockIdx.x * 128;
    const int wm = (wave >> 1) * 64, wn = (wave & 1) * 64;

    f32x4 acc[4][4];
    #pragma unroll
    for (int i = 0; i < 4; i++)
        #pragma unroll
        for (int j = 0; j < 4; j++) acc[i][j] = (f32x4){0.f, 0.f, 0.f, 0.f};

    for (int k0 = 0; k0 < 2048; k0 += 32) {
        __syncthreads();
        #pragma unroll
        for (int it = 0; it < 2; it++) {
            const int f = it * 256 + tid;
            const int r = f >> 2, c8 = (f & 3) * 8;
            *(bf16x8*)&As[r][c8] = *(const bf16x8*)(A + (long)(m0 + r) * 2048 + k0 + c8);
            *(bf16x8*)&Bs[r][c8] = *(const bf16x8*)(Bt + (long)(n0 + r) * 2048 + k0 + c8);
        }
        __syncthreads();
        bf16x8 af[4], bf_[4];
        #pragma unroll
        for (int mt = 0; mt < 4; mt++)
            af[mt] = *(const bf16x8*)&As[wm + mt * 16 + l16][quad * 8];
        #pragma unroll
        for (int nt = 0; nt < 4; nt++)
            bf_[nt] = *(const bf16x8*)&Bs[wn + nt * 16 + l16][quad * 8];
        #pragma unroll
        for (int mt = 0; mt < 4; mt++)
            #pragma unroll
            for (int nt = 0; nt < 4; nt++)
                acc[mt][nt] = __builtin_amdgcn_mfma_f32_16x16x32_bf16(af[mt], bf_[nt], acc[mt][nt], 0, 0, 0);
    }

    #pragma unroll
    for (int mt = 0; mt < 4; mt++) {
        #pragma unroll
        for (int r = 0; r < 4; r++) {
            const int row = m0 + wm + mt * 16 + quad * 4 + r;
            float* dst = C + (long)row * 2048 + n0 + wn;
            #pragma unroll
            for (int nt = 0; nt < 4; nt++)
                dst[nt * 16 + l16] = acc[mt][nt][r];
        }
    }
}

// ---------------------------------------------------------------------------
// Exact 0.995-quantile via radix-select on |x| bit patterns.
// ---------------------------------------------------------------------------
__global__ void quant_init(int* __restrict__ qP, int* __restrict__ qC)
{
    const int t = threadIdx.x;
    if (t < 40) { qP[t] = 0; qC[t] = 0; }
}

__global__ __launch_bounds__(256) void hist_zero(int* __restrict__ hist)
{
    hist[blockIdx.x * 256 + threadIdx.x] = 0;
}

__global__ __launch_bounds__(256) void hist_build(
    const float* __restrict__ qbuf, const float* __restrict__ kfb,
    const int* __restrict__ qP, int* __restrict__ hist, int level)
{
    __shared__ int lh[4096];
    const int tid = threadIdx.x;
    const int job = blockIdx.x >> 5, sub = blockIdx.x & 31;
    for (int i = tid; i < 4096; i += 256) lh[i] = 0;
    __syncthreads();
    const int head = job >> 1;
    const int pref = qP[job];
    for (int it = 0; it < 64; it++) {
        const int e = sub * 16384 + it * 256 + tid;
        const int bb = e >> 18, off = e & 262143;
        float v;
        if (head < 16) v = qbuf[(bb * 16 + head) * 262144 + off];
        else           v = kfb[(bb * 4 + (head - 16)) * 262144 + off];
        const unsigned u = __float_as_uint(fabsf(v));
        int bin = -1;
        if (level == 0)      bin = (int)(u >> 20);
        else if (level == 1) { if ((int)(u >> 20) == pref) bin = (int)((u >> 8) & 4095u); }
        else                 { if ((int)(u >> 8)  == pref) bin = (int)(u & 255u); }
        if (bin >= 0) atomicAdd(&lh[bin], 1);
    }
    __syncthreads();
    for (int i = tid; i < 4096; i += 256) {
        const int c = lh[i];
        if (c) atomicAdd(&hist[job * 4096 + i], c);
    }
}

__global__ __launch_bounds__(256) void hist_scan(
    int* __restrict__ qP, int* __restrict__ qC,
    const int* __restrict__ hist, int level)
{
    __shared__ int psum[256];
    __shared__ int sel[2];
    const int job = blockIdx.x, tid = threadIdx.x;
    const int target = (job & 1) ? 521666 : 521665;
    const int t = target - qC[job];
    int loc[16]; int s = 0;
    const int* hb = hist + job * 4096 + tid * 16;
    #pragma unroll
    for (int i = 0; i < 16; i++) { loc[i] = hb[i]; s += loc[i]; }
    psum[tid] = s;
    __syncthreads();
    if (tid == 0) {
        int cum = 0, pick = 255, pcum = 0; bool fnd = false;
        for (int i = 0; i < 256; i++) {
            const int c = psum[i];
            if (!fnd && cum + c > t) { pick = i; pcum = cum; fnd = true; }
            cum += c;
        }
        if (!fnd) pcum = cum - psum[255];
        sel[0] = pick; sel[1] = pcum;
    }
    __syncthreads();
    if (tid == sel[0]) {
        int c = sel[1];
        int bin = 15;
        #pragma unroll
        for (int i = 0; i < 16; i++) {
            if (c + loc[i] > t) { bin = i; break; }
            c += loc[i];
        }
        const int gbin = tid * 16 + bin;
        int p = qP[job];
        if (level == 0)      p = gbin;
        else if (level == 1) p = (p << 12) | gbin;
        else                 p = (p << 8) | gbin;
        qP[job] = p;
        qC[job] = qC[job] + c;
    }
}

__global__ void finalize_scales(const int* __restrict__ qP,
                                float* __restrict__ q_scale, float* __restrict__ k_scale)
{
    const int tid = threadIdx.x;
    const double pos = 0.995 * 524287.0;
    const float fr = (float)(pos - floor(pos));
    if (tid < 16) {
        const float v0 = __uint_as_float((unsigned)qP[2 * tid]);
        const float v1 = __uint_as_float((unsigned)qP[2 * tid + 1]);
        const float am = v0 + fr * (v1 - v0);
        q_scale[tid] = fmaxf(am, 1e-6f) / 7.0f;
    } else if (tid < 32) {
        const int h = tid - 16;
        const int job = (16 + (h >> 2)) * 2;
        const float v0 = __uint_as_float((unsigned)qP[job]);
        const float v1 = __uint_as_float((unsigned)qP[job + 1]);
        const float am = v0 + fr * (v1 - v0);
        k_scale[h] = fmaxf(am, 1e-6f) / 7.0f;
    }
}

__global__ __launch_bounds__(256) void quant_q(
    float* __restrict__ qbuf, const float* __restrict__ q_scale)
{
    const int i = blockIdx.x * 256 + threadIdx.x;
    const int h = (i >> 18) & 15;
    const float sc = q_scale[h];
    float v = rintf(qbuf[i] / sc);
    v = fminf(fmaxf(v, -7.f), 7.f);
    qbuf[i] = v;
}

__global__ __launch_bounds__(256) void quant_k(
    const float* __restrict__ kfb, float* __restrict__ kout,
    const float* __restrict__ k_scale)
{
    const int i = blockIdx.x * 256 + threadIdx.x;
    const int h = (i >> 18) & 15;
    const int bb = i >> 22;
    const int rest = i & 262143;
    const float v = kfb[(bb * 4 + (h >> 2)) * 262144 + rest];
    const float sc = k_scale[h];
    float qv = rintf(v / sc);
    qv = fminf(fmaxf(qv, -7.f), 7.f);
    kout[i] = qv;
}

// ---------------------------------------------------------------------------
extern "C" void kernel_launch(void* const* d_in, const int* in_sizes, int n_in,
                              void* d_out, int out_size, void* d_ws, size_t ws_size,
                              hipStream_t stream)
{
    const float* hs   = (const float*)d_in[0];
    const float* cosb = (const float*)d_in[1];
    const float* sinb = (const float*)d_in[2];
    const float* Wq = (const float*)d_in[4];
    const float* Wk = (const float*)d_in[5];
    const float* Wv = (const float*)d_in[6];
    const float* Wo = (const float*)d_in[7];

    float* out     = (float*)d_out;
    float* qbuf    = out + 8388608;     // q_int8 region: q fp32, quantized in place
    float* q_scale = out + 16777216;
    float* kqout   = out + 16777232;    // k_int8 region: doubles as bf16 scratch
    float* k_scale = out + 25165840;

    // bf16 scratch inside the (written-last) k_int8 region
    bf16* qb16 = (bf16*)kqout;
    bf16* kb16 = qb16 + 8388608;
    bf16* vtb  = kb16 + 2097152;

    float* wsf = (float*)d_ws;          // ~43 MB used
    bf16*  ctx16 = (bf16*)wsf;                 // 4096x2048 bf16
    float* kfb   = wsf + 4194304;              // (B,NKV,S,D) fp32
    float* vfb   = wsf + 6291456;
    bf16*  woT   = (bf16*)(wsf + 8388608);     // WoT[n][k] bf16
    int*   qP    = (int*)(wsf + 10485760);
    int*   qC    = qP + 64;
    int*   hist  = qP + 128;

    sgemm_qkv<<<dim3(24, 32), 256, 0, stream>>>(hs, Wq, Wk, Wv, qbuf, kfb, vfb);
    rope_cvt_k<<<16384, 256, 0, stream>>>(qbuf, qb16, cosb, sinb, 16);
    rope_cvt_k<<<4096, 256, 0, stream>>>(kfb, kb16, cosb, sinb, 4);
    transpose_v<<<dim3(64, 4, 8), 256, 0, stream>>>(vfb, vtb);
    transpose_wo<<<dim3(64, 64), 256, 0, stream>>>(Wo, woT);

    attn_mfma<<<dim3(32, 16, 2), 256, 0, stream>>>(qb16, kb16, vtb, ctx16);
    gemm_o_mfma<<<dim3(16, 32), 256, 0, stream>>>(ctx16, woT, out);

    quant_init<<<1, 64, 0, stream>>>(qP, qC);
    for (int lvl = 0; lvl < 3; lvl++) {
        hist_zero<<<640, 256, 0, stream>>>(hist);
        hist_build<<<1280, 256, 0, stream>>>(qbuf, kfb, qP, hist, lvl);
        hist_scan<<<40, 256, 0, stream>>>(qP, qC, hist, lvl);
    }
    finalize_scales<<<1, 64, 0, stream>>>(qP, q_scale, k_scale);

    quant_q<<<32768, 256, 0, stream>>>(qbuf, q_scale);
    quant_k<<<32768, 256, 0, stream>>>(kfb, kqout, k_scale);
}